// Round 1
// baseline (1088.742 us; speedup 1.0000x reference)
//
#include <hip/hip_runtime.h>

// Problem constants (match reference)
constexpr int Bn   = 32;
constexpr int Ln   = 1855;
constexpr int Kn   = 7;
constexpr int Tn   = 40;
constexpr int CIn  = 8;
constexpr int COn  = 32;
constexpr int TKSn = 5;
constexpr int TOn  = Tn - TKSn + 1;  // 36

// LDS sizes
constexpr int XS_FLOATS = Kn * Tn * CIn;          // 2240 (7 x 320)
constexpr int WS_FLOATS = Kn * TKSn * CIn * COn;  // 8960

__global__ __launch_bounds__(256) void indexed_conv_kernel(
    const float* __restrict__ x,      // (B, L, T, CIn)
    const int*   __restrict__ nbr,    // (L, K)
    const float* __restrict__ w,      // (K, TKS, CIn, COn)
    const float* __restrict__ bias,   // (COn,)
    float*       __restrict__ out)    // (B, L, TOn, COn)
{
    // xs padded so the unconditional 18-float4 window load never runs past the array
    __shared__ float xs[XS_FLOATS + 16];
    __shared__ float ws[WS_FLOATS];

    const int l   = blockIdx.x;
    const int b   = blockIdx.y;
    const int tid = threadIdx.x;

    // ---- stage weights: 8960 floats = 2240 float4, straight copy (layout kept) ----
    {
        const float4* src = (const float4*)w;
        float4*       dst = (float4*)ws;
        for (int p = tid; p < WS_FLOATS / 4; p += 256) dst[p] = src[p];
    }

    // ---- stage gathered neighbor rows: 7 x 320 floats = 560 float4 ----
    {
        const float4* xsrc = (const float4*)x;
        float4*       xdst = (float4*)xs;
        for (int p = tid; p < (Kn * Tn * CIn) / 4; p += 256) {
            const int k = p / (Tn * CIn / 4);          // 80 float4 per k
            const int q = p - k * (Tn * CIn / 4);
            const int l2 = nbr[l * Kn + k];
            float4 v = make_float4(0.f, 0.f, 0.f, 0.f);
            if (l2 >= 0) {
                v = xsrc[((size_t)b * Ln + (size_t)l2) * (Tn * CIn / 4) + q];
            }
            xdst[p] = v;
        }
    }
    __syncthreads();

    // ---- compute ----
    const int o  = tid & 31;   // output channel
    const int tg = tid >> 5;   // t-group 0..7
    const int tstart = (tg < 4) ? tg * 5 : 20 + (tg - 4) * 4;
    const int tcnt   = (tg < 4) ? 5 : 4;

    float acc[5] = {0.f, 0.f, 0.f, 0.f, 0.f};

    for (int k = 0; k < Kn; ++k) {
        // load 72-float x window into registers (18 ds_read_b128)
        float xw[72];
        const float4* xsrc4 = (const float4*)&xs[k * (Tn * CIn) + tstart * CIn];
        #pragma unroll
        for (int q = 0; q < 18; ++q) {
            float4 v = xsrc4[q];
            xw[4 * q + 0] = v.x;
            xw[4 * q + 1] = v.y;
            xw[4 * q + 2] = v.z;
            xw[4 * q + 3] = v.w;
        }
        const float* wk = ws + k * (TKSn * CIn * COn);  // [tau][i][o]
        #pragma unroll
        for (int tau = 0; tau < TKSn; ++tau) {
            #pragma unroll
            for (int i = 0; i < CIn; ++i) {
                const float wv = wk[(tau * CIn + i) * COn + o];  // broadcast ds_read_b32
                #pragma unroll
                for (int j = 0; j < 5; ++j) {
                    acc[j] = fmaf(xw[(j + tau) * CIn + i], wv, acc[j]);
                }
            }
        }
    }

    // ---- epilogue: bias + store (coalesced over o) ----
    const float bv = bias[o];
    const size_t obase = (((size_t)b * Ln + (size_t)l) * TOn) * COn + o;
    for (int j = 0; j < tcnt; ++j) {
        out[obase + (size_t)(tstart + j) * COn] = acc[j] + bv;
    }
}

extern "C" void kernel_launch(void* const* d_in, const int* in_sizes, int n_in,
                              void* d_out, int out_size, void* d_ws, size_t ws_size,
                              hipStream_t stream) {
    const float* x    = (const float*)d_in[0];
    const int*   nbr  = (const int*)d_in[1];
    const float* w    = (const float*)d_in[2];
    const float* bias = (const float*)d_in[3];
    float*       out  = (float*)d_out;

    dim3 grid(Ln, Bn);
    indexed_conv_kernel<<<grid, dim3(256), 0, stream>>>(x, nbr, w, bias, out);
}

// Round 2
// 542.482 us; speedup vs baseline: 2.0070x; 2.0070x over previous
//
#include <hip/hip_runtime.h>

// Problem constants
constexpr int Bn = 32, Ln = 1855, Kn = 7, Tn = 40, CIn = 8, COn = 32, TKSn = 5, TOn = 36;
constexpr int BG   = 8;               // b per block
constexpr int KRED = Kn * TKSn * CIn; // 280
constexpr int WROW = 296;             // padded wt row length (bf16 elems), zero-filled [280,296)
constexpr int XS_ELEMS = BG * Kn * Tn * CIn; // 17920 bf16

typedef __attribute__((ext_vector_type(8))) short bf16x8; // 8 bf16 = 4 VGPRs
typedef __attribute__((ext_vector_type(4))) float f32x4;  // MFMA C/D

__device__ inline unsigned short f2bf(float f) {
    unsigned u = __builtin_bit_cast(unsigned, f);
    u += 0x7fffu + ((u >> 16) & 1u); // RNE
    return (unsigned short)(u >> 16);
}

__global__ __launch_bounds__(256) void conv_mfma(
    const float* __restrict__ x,      // (B, L, T, CIn)
    const int*   __restrict__ nbr,    // (L, K)
    const float* __restrict__ w,      // (K, TKS, CIn, COn)
    const float* __restrict__ bias,   // (COn,)
    float*       __restrict__ out)    // (B, L, TOn, COn)
{
    // xs: gathered neighbor rows, bf16, layout [b_local][k][t][i], i contiguous.
    // +8 zero pad row used as the A-source for the padded K chunk (quad==3, c==8).
    __shared__ unsigned short xs[XS_ELEMS + 8];
    __shared__ unsigned short wt[COn * WROW]; // W^T: [o][k_red], row padded to 296

    const int tid = threadIdx.x;
    const int l   = blockIdx.x;
    const int bg  = blockIdx.y;

    // ---- stage weights: w[((k*5+tau)*8+i)*32+o] -> wt[o][k_red] (bf16) ----
    for (int p = tid; p < KRED * COn; p += 256) { // 8960
        int o  = p & 31;
        int kr = p >> 5;                          // (k*5+tau)*8+i
        wt[o * WROW + kr] = f2bf(w[p]);
    }
    for (int p = tid; p < COn * (WROW - KRED); p += 256) { // zero pad cols
        int o = p >> 4;
        wt[o * WROW + KRED + (p & 15)] = 0;
    }
    if (tid < 8) xs[XS_ELEMS + tid] = 0; // zero A-pad row

    // ---- stage gathered x: fp32 global -> bf16 LDS (masked gather) ----
    for (int p = tid; p < BG * Kn * 80; p += 256) { // 4480 float4
        int b_local = p / 560;          // 560 float4 per b_local
        int r = p - b_local * 560;
        int k = r / 80;                 // 80 float4 per (b,k) row
        int q = r - k * 80;
        int l2 = nbr[l * Kn + k];
        float4 v = make_float4(0.f, 0.f, 0.f, 0.f);
        if (l2 >= 0)
            v = ((const float4*)x)[((size_t)(bg * BG + b_local) * Ln + l2) * 80 + q];
        ushort4 pk;
        pk.x = f2bf(v.x); pk.y = f2bf(v.y); pk.z = f2bf(v.z); pk.w = f2bf(v.w);
        *(ushort4*)&xs[p * 4] = pk;
    }
    __syncthreads();

    // ---- MFMA compute: rows m = b_local*36 + t (288), cols o (32), K 288 ----
    const int wave = tid >> 6;
    const int lane = tid & 63;
    const int quad = lane >> 4;
    const int lrow = lane & 15;
    const int o_base  = (wave & 1) * 16;  // o col-tile
    const int rt_base = (wave >> 1) * 9;  // 9 row-tiles of 16 per wave

    // Preload all 9 B fragments (register-resident across row-tiles).
    // B[k_red = c*32 + quad*8 + j][n = o_base+lrow] == wt row read, contiguous k.
    bf16x8 bfrag[9];
    #pragma unroll
    for (int c = 0; c < 9; ++c)
        bfrag[c] = *(const bf16x8*)&wt[(o_base + lrow) * WROW + c * 32 + quad * 8];

    const float bv = bias[o_base + lrow];

    #pragma unroll
    for (int g = 0; g < 3; ++g) {       // 3 groups x 3 row-tiles (ILP)
        const int rt0 = rt_base + g * 3;
        f32x4 acc0 = {0.f,0.f,0.f,0.f}, acc1 = acc0, acc2 = acc0;
        const int m0 = (rt0 + 0) * 16 + lrow;
        const int m1 = (rt0 + 1) * 16 + lrow;
        const int m2 = (rt0 + 2) * 16 + lrow;
        const int bl0 = m0 / 36, t0 = m0 - bl0 * 36;
        const int bl1 = m1 / 36, t1 = m1 - bl1 * 36;
        const int bl2 = m2 / 36, t2 = m2 - bl2 * 36;
        const int base0 = bl0 * 2240 + t0 * 8;
        const int base1 = bl1 * 2240 + t1 * 8;
        const int base2 = bl2 * 2240 + t2 * 8;
        #pragma unroll
        for (int c = 0; c < 9; ++c) {
            const int p = c * 4 + quad;         // (k,tau) pair index, 36th is pad
            const int knbr = p / 5, tau = p - knbr * 5;
            const int koff = knbr * 320 + tau * 8;
            int o0 = base0 + koff, o1 = base1 + koff, o2 = base2 + koff;
            if (c == 8 && quad == 3) { o0 = XS_ELEMS; o1 = XS_ELEMS; o2 = XS_ELEMS; }
            bf16x8 a0 = *(const bf16x8*)&xs[o0];
            bf16x8 a1 = *(const bf16x8*)&xs[o1];
            bf16x8 a2 = *(const bf16x8*)&xs[o2];
            acc0 = __builtin_amdgcn_mfma_f32_16x16x32_bf16(a0, bfrag[c], acc0, 0, 0, 0);
            acc1 = __builtin_amdgcn_mfma_f32_16x16x32_bf16(a1, bfrag[c], acc1, 0, 0, 0);
            acc2 = __builtin_amdgcn_mfma_f32_16x16x32_bf16(a2, bfrag[c], acc2, 0, 0, 0);
        }
        // epilogue: C/D layout col=lane&15, row=quad*4+reg  [m89/m91 verified]
        #pragma unroll
        for (int i = 0; i < 3; ++i) {
            const f32x4 acc = (i == 0) ? acc0 : ((i == 1) ? acc1 : acc2);
            const int rt = rt0 + i;
            #pragma unroll
            for (int reg = 0; reg < 4; ++reg) {
                const int m  = rt * 16 + quad * 4 + reg;
                const int bl = m / 36, t = m - bl * 36;
                const size_t off =
                    (((size_t)(bg * BG + bl) * Ln + l) * TOn + t) * COn + o_base + lrow;
                out[off] = acc[reg] + bv;
            }
        }
    }
}

extern "C" void kernel_launch(void* const* d_in, const int* in_sizes, int n_in,
                              void* d_out, int out_size, void* d_ws, size_t ws_size,
                              hipStream_t stream) {
    const float* x    = (const float*)d_in[0];
    const int*   nbr  = (const int*)d_in[1];
    const float* w    = (const float*)d_in[2];
    const float* bias = (const float*)d_in[3];
    float*       out  = (float*)d_out;

    dim3 grid(Ln, Bn / BG); // (1855, 4)
    conv_mfma<<<grid, dim3(256), 0, stream>>>(x, nbr, w, bias, out);
}